// Round 19
// baseline (125.057 us; speedup 1.0000x reference)
//
#include <hip/hip_runtime.h>

#define IN_CH 128
#define NEG_SLOPE 0.2f
#define BINSZ 8000          // nodes per bin; LDS = 8000*8 = 64000 B
#define NBINS 13
#define NW 8192             // global wave count for count/place (must match grids)
#define MAX_SGH 39
#define MAX_BPB 40
#define PB1024 256          // place blocks per half @1024 threads (16 waves each): 256*16 = NW/2
#define HMAXB 30
#define F_NUM 2097152.0f    // 2^21 fixed-point scale for num = e*hs  (|num| < 1024)
#define F_DEN 16777216.0f   // 2^24 fixed-point scale for den = e     (den < 256)
#define INV_F_NUM 4.76837158203125e-7f
#define INV_F_DEN 5.9604644775390625e-8f

typedef int   vi4 __attribute__((ext_vector_type(4)));
typedef float vf4 __attribute__((ext_vector_type(4)));

__device__ __forceinline__ float lrelu(float v) { return v > 0.f ? v : NEG_SLOPE * v; }
__device__ __forceinline__ unsigned enc_max(float f) {
    unsigned u = __float_as_uint(f);
    return (u & 0x80000000u) ? ~u : (u | 0x80000000u);   // monotone float->uint
}
__device__ __forceinline__ float dec_max(unsigned e) {
    return (e & 0x80000000u) ? __uint_as_float(e ^ 0x80000000u) : __uint_as_float(~e);
}
__device__ __forceinline__ unsigned bf16_rne(float f) {   // top-16 bits, round-nearest-even
    unsigned u = __float_as_uint(f);
    return (u + 0x7FFFu + ((u >> 16) & 1u)) >> 16;
}

// ---------- proj body ----------
__device__ __forceinline__ void do_proj(const float* __restrict__ x, const float* __restrict__ W,
                                        const float* __restrict__ att_dst,
                                        float* __restrict__ h, float* __restrict__ ad_h,
                                        int n, int wid, int nwaves) {
    int lane = threadIdx.x & 63;
    int half = lane >> 5;
    int hl   = lane & 31;

    vf4 w4 = reinterpret_cast<const vf4*>(W)[hl];
    const float ad = att_dst[0];

    int npair = n >> 1;
    for (int p0 = wid * 4; p0 < npair; p0 += nwaves * 4) {
        float s[4];
        #pragma unroll
        for (int k = 0; k < 4; ++k) {
            int p = p0 + k;
            s[k] = 0.f;
            if (p < npair) {
                int row = 2 * p + half;
                vf4 v = __builtin_nontemporal_load(
                    reinterpret_cast<const vf4*>(x + (size_t)row * IN_CH) + hl);
                s[k] = v.x * w4.x + v.y * w4.y + v.z * w4.z + v.w * w4.w;
            }
        }
        #pragma unroll
        for (int k = 0; k < 4; ++k) {
            #pragma unroll
            for (int off = 16; off > 0; off >>= 1) s[k] += __shfl_xor(s[k], off);
        }
        #pragma unroll
        for (int k = 0; k < 4; ++k) {
            int p = p0 + k;
            if (p < npair && hl == 0) {
                int row = 2 * p + half;
                h[row] = s[k];
                ad_h[row] = s[k] * ad;
            }
        }
    }
    if ((n & 1) && wid == 0) {
        int row = n - 1;
        vf4 v = reinterpret_cast<const vf4*>(x + (size_t)row * IN_CH)[hl];
        float s = v.x * w4.x + v.y * w4.y + v.z * w4.z + v.w * w4.w;
        #pragma unroll
        for (int off = 16; off > 0; off >>= 1) s += __shfl_xor(s, off);
        if (lane == 0) { h[row] = s; ad_h[row] = s * ad; }
    }
}

// ---------- standalone proj (fallback path) ----------
__global__ __launch_bounds__(256)
void proj_kernel(const float* __restrict__ x, const float* __restrict__ W,
                 const float* __restrict__ att_dst,
                 float* __restrict__ h, float* __restrict__ ad_h, int n) {
    int wid    = (blockIdx.x * blockDim.x + threadIdx.x) >> 6;
    int nwaves = (gridDim.x * blockDim.x) >> 6;
    do_proj(x, W, att_dst, h, ad_h, n, wid, nwaves);
}

// ---------- 2a) FUSED count (vec4 + per-wave LDS counters) || proj ----------
__global__ __launch_bounds__(256)
void count_proj_kernel(const int* __restrict__ dst_idx, int* __restrict__ wc, int E,
                       const float* __restrict__ x, const float* __restrict__ W,
                       const float* __restrict__ att_dst,
                       float* __restrict__ h, float* __restrict__ ad_h, int n) {
    __shared__ int cnt[4][NBINS];
    int b = blockIdx.x;
    int role = b % 3;
    if (role == 2) {
        int qid = b / 3;                       // [0,1024)
        int wid = qid * 4 + (threadIdx.x >> 6);
        do_proj(x, W, att_dst, h, ad_h, n, wid, 4096);
        return;
    }
    int pid  = (b / 3) * 2 + role;             // [0,2048)
    int lane = threadIdx.x & 63, wv = threadIdx.x >> 6;
    int g = pid * 4 + wv;                      // [0, NW)
    if (lane < NBINS) cnt[wv][lane] = 0;       // wave-private counters

    long long E4 = E >> 2;
    long long e0 = 4 * (E4 * g / NW);
    long long e1 = (g == NW - 1) ? (long long)E : 4 * (E4 * (g + 1) / NW);
    for (long long i0 = e0; i0 < e1; i0 += 256) {
        long long i = i0 + 4 * lane;
        if (i < e1) {
            vi4 d4 = __builtin_nontemporal_load(reinterpret_cast<const vi4*>(dst_idx + i));
            atomicAdd(&cnt[wv][d4.x / BINSZ], 1);
            atomicAdd(&cnt[wv][d4.y / BINSZ], 1);
            atomicAdd(&cnt[wv][d4.z / BINSZ], 1);
            atomicAdd(&cnt[wv][d4.w / BINSZ], 1);
        }
    }
    if (lane < NBINS) wc[lane * NW + g] = cnt[wv][lane];
}

// ---------- 2b) scan pipeline ----------
__global__ __launch_bounds__(256)
void scanA_kernel(const int* __restrict__ wc, int* __restrict__ bsum) {
    __shared__ int wt[4];
    int t = threadIdx.x, lane = t & 63, wv = t >> 6;
    vi4 c = *reinterpret_cast<const vi4*>(wc + blockIdx.x * 1024 + 4 * t);
    int s = c.x + c.y + c.z + c.w;
    #pragma unroll
    for (int off = 32; off > 0; off >>= 1) s += __shfl_xor(s, off);
    if (lane == 0) wt[wv] = s;
    __syncthreads();
    if (t == 0) bsum[blockIdx.x] = wt[0] + wt[1] + wt[2] + wt[3];
}

__global__ __launch_bounds__(128)
void scanB_kernel(const int* __restrict__ bsum, int* __restrict__ bbase,
                  int* __restrict__ rbase, int* __restrict__ hist,
                  unsigned* __restrict__ maxenc, int nchunk) {
    __shared__ int sb[129];
    __shared__ int wt[2];
    int t = threadIdx.x, lane = t & 63, wv = t >> 6;
    if (t < 2) maxenc[t] = 0u;                  // zero for later atomicMax
    int v = (t < nchunk) ? bsum[t] : 0;
    int inc = v;
    #pragma unroll
    for (int d2 = 1; d2 < 64; d2 <<= 1) { int u = __shfl_up(inc, d2); if (lane >= d2) inc += u; }
    if (lane == 63) wt[wv] = inc;
    __syncthreads();
    int excl = ((wv == 1) ? wt[0] : 0) + inc - v;
    sb[t] = excl;
    if (t == 127) sb[128] = excl + v;   // grand total
    __syncthreads();
    if (t < nchunk) bbase[t] = sb[t];
    if (t < NBINS) {
        int rb = sb[t * (NW / 1024)];
        rbase[t] = rb;
        int nb = (t == NBINS - 1) ? sb[128] : sb[(t + 1) * (NW / 1024)];
        hist[t] = nb - rb;
    }
}

__global__ __launch_bounds__(256)
void scanC_kernel(const int* __restrict__ wc, const int* __restrict__ bbase,
                  int* __restrict__ wbase) {
    __shared__ int wt[4];
    int t = threadIdx.x, lane = t & 63, wv = t >> 6;
    int base = blockIdx.x * 1024 + 4 * t;
    vi4 c = *reinterpret_cast<const vi4*>(wc + base);
    int s0 = c.x, s1 = s0 + c.y, s2 = s1 + c.z, s3 = s2 + c.w;
    int tot = s3;
    int inc = tot;
    #pragma unroll
    for (int d2 = 1; d2 < 64; d2 <<= 1) { int u = __shfl_up(inc, d2); if (lane >= d2) inc += u; }
    if (lane == 63) wt[wv] = inc;
    __syncthreads();
    int wb = 0;
    for (int k = 0; k < wv; ++k) wb += wt[k];
    int excl = bbase[blockIdx.x] + wb + inc - tot;
    vi4 o; o.x = excl; o.y = excl + s0; o.z = excl + s1; o.w = excl + s2;
    *reinterpret_cast<vi4*>(wbase + base) = o;
}

// ---------- place body: one wave, r16-proven form (1-deep idx prefetch) ----------
__device__ __forceinline__ void place_wave(const int* __restrict__ src_idx,
                                           const int* __restrict__ dst_idx,
                                           const float* __restrict__ h,
                                           const int* __restrict__ wbase,
                                           unsigned* __restrict__ rec, int E,
                                           int g, int* ccur) {
    int lane = threadIdx.x & 63;
    if (lane < NBINS) ccur[lane] = wbase[lane * NW + g];   // wave-private: no barrier

    long long E4 = E >> 2;
    long long e0 = 4 * (E4 * (long long)g / NW);
    long long e1 = (g == NW - 1) ? (long long)E : 4 * (E4 * (long long)(g + 1) / NW);

    long long i = e0 + 4 * (long long)lane;
    bool have = (i < e1);
    vi4 d4 = {0,0,0,0}, s4 = {0,0,0,0};
    if (have) {
        d4 = __builtin_nontemporal_load(reinterpret_cast<const vi4*>(dst_idx + i));
        s4 = __builtin_nontemporal_load(reinterpret_cast<const vi4*>(src_idx + i));
    }
    while (have) {
        long long nx = i + 256;
        bool nhave = (nx < e1);
        vi4 d4n = {0,0,0,0}, s4n = {0,0,0,0};
        if (nhave) {                            // prefetch next iteration's indices
            d4n = __builtin_nontemporal_load(reinterpret_cast<const vi4*>(dst_idx + nx));
            s4n = __builtin_nontemporal_load(reinterpret_cast<const vi4*>(src_idx + nx));
        }
        float h0 = h[s4.x], h1 = h[s4.y], h2 = h[s4.z], h3 = h[s4.w];
        int b0 = d4.x / BINSZ, b1 = d4.y / BINSZ, b2 = d4.z / BINSZ, b3 = d4.w / BINSZ;
        int p0 = atomicAdd(&ccur[b0], 1);
        int p1 = atomicAdd(&ccur[b1], 1);
        int p2 = atomicAdd(&ccur[b2], 1);
        int p3 = atomicAdd(&ccur[b3], 1);
        rec[p0] = ((unsigned)(d4.x - b0 * BINSZ) << 16) | bf16_rne(h0);  // normal stores
        rec[p1] = ((unsigned)(d4.y - b1 * BINSZ) << 16) | bf16_rne(h1);
        rec[p2] = ((unsigned)(d4.z - b2 * BINSZ) << 16) | bf16_rne(h2);
        rec[p3] = ((unsigned)(d4.w - b3 * BINSZ) << 16) | bf16_rne(h3);
        i = nx; d4 = d4n; s4 = s4n; have = nhave;
    }
}

// ---------- gather body: process rec range [g0,g1) into s_acc, dump to outp ----------
__device__ __forceinline__ void gather_range(const unsigned* __restrict__ rec,
                                             const float* __restrict__ adw,
                                             float as, float L,
                                             long long g0, long long g1,
                                             unsigned long long* s_acc,
                                             unsigned long long* __restrict__ outp) {
    {   // zero LDS with 16B stores
        vi4 z = {0, 0, 0, 0};
        for (int k = threadIdx.x; k < BINSZ / 2; k += 1024)
            *reinterpret_cast<vi4*>(&s_acc[2 * k]) = z;
    }
    __syncthreads();

    auto process1 = [&](unsigned q) {
        int ri = q >> 16;
        float h0 = __uint_as_float(q << 16);            // bf16 -> f32
        float e0 = __expf(lrelu(fmaf(h0, as, adw[ri])) - L);
        unsigned long long p0 = ((unsigned long long)(long long)__float2int_rn(e0 * h0 * F_NUM) << 32)
                              + __float2uint_rn(e0 * F_DEN);
        atomicAdd(&s_acc[ri], p0);
    };

    long long a0 = (g0 + 3) & ~3LL;     // aligned vector range [a0, a1)
    long long a1 = g1 & ~3LL;
    long long headEnd, tail0;
    if (a0 <= a1) { headEnd = a0; tail0 = a1; }
    else          { headEnd = g1; tail0 = g1; a0 = 0; a1 = 0; }

    for (long long i = g0 + threadIdx.x; i < headEnd; i += 1024) process1(rec[i]);

    long long i = a0 + 4 * (long long)threadIdx.x;
    vi4 q = {0,0,0,0};
    bool have = (i < a1);
    if (have) q = __builtin_nontemporal_load(reinterpret_cast<const vi4*>(rec + i));
    while (have) {
        long long nx = i + 4096;
        bool nhave = (nx < a1);
        vi4 nq = {0,0,0,0};
        if (nhave) nq = __builtin_nontemporal_load(reinterpret_cast<const vi4*>(rec + nx));
        unsigned u0=(unsigned)q.x, u1=(unsigned)q.y, u2=(unsigned)q.z, u3=(unsigned)q.w;
        int r0i=u0>>16, r1i=u1>>16, r2i=u2>>16, r3i=u3>>16;
        float h0=__uint_as_float(u0<<16), h1=__uint_as_float(u1<<16);
        float h2=__uint_as_float(u2<<16), h3=__uint_as_float(u3<<16);
        float e0 = __expf(lrelu(fmaf(h0, as, adw[r0i])) - L);
        float e1 = __expf(lrelu(fmaf(h1, as, adw[r1i])) - L);
        float e2 = __expf(lrelu(fmaf(h2, as, adw[r2i])) - L);
        float e3 = __expf(lrelu(fmaf(h3, as, adw[r3i])) - L);
        unsigned long long p0 = ((unsigned long long)(long long)__float2int_rn(e0 * h0 * F_NUM) << 32) + __float2uint_rn(e0 * F_DEN);
        unsigned long long p1 = ((unsigned long long)(long long)__float2int_rn(e1 * h1 * F_NUM) << 32) + __float2uint_rn(e1 * F_DEN);
        unsigned long long p2 = ((unsigned long long)(long long)__float2int_rn(e2 * h2 * F_NUM) << 32) + __float2uint_rn(e2 * F_DEN);
        unsigned long long p3 = ((unsigned long long)(long long)__float2int_rn(e3 * h3 * F_NUM) << 32) + __float2uint_rn(e3 * F_DEN);
        atomicAdd(&s_acc[r0i], p0);
        atomicAdd(&s_acc[r1i], p1);
        atomicAdd(&s_acc[r2i], p2);
        atomicAdd(&s_acc[r3i], p3);
        i = nx; q = nq; have = nhave;
    }

    for (long long i2 = tail0 + threadIdx.x; i2 < g1; i2 += 1024) process1(rec[i2]);
    __syncthreads();

    for (int k = threadIdx.x; k < BINSZ / 2; k += 1024) {
        vi4 v = *reinterpret_cast<const vi4*>(&s_acc[2 * k]);
        __builtin_nontemporal_store(v, reinterpret_cast<vi4*>(outp + 2 * k));
    }
}

// ---------- 2c) launch3: place(half1) || hmax ----------
__global__ __launch_bounds__(1024)
void place1_hmax_kernel(const int* __restrict__ src_idx, const int* __restrict__ dst_idx,
                        const float* __restrict__ h, const int* __restrict__ wbase,
                        unsigned* __restrict__ rec, int E,
                        const float* __restrict__ att_src, const float* __restrict__ att_dst,
                        unsigned* __restrict__ maxenc, int n) {
    __shared__ int ccur[16][NBINS];
    int b = blockIdx.x;
    if (b < PB1024) {
        int wv = threadIdx.x >> 6;
        place_wave(src_idx, dst_idx, h, wbase, rec, E, b * 16 + wv, ccur[wv]);
        return;
    }
    // ---- hmax role ----
    int bid = b - PB1024;                        // [0, HMAXB)
    const float as = att_src[0];
    const float ad = att_dst[0];
    float m1 = -1e30f, m2 = -1e30f;
    for (int i = bid * 1024 + threadIdx.x; i < n; i += HMAXB * 1024) {
        float v = h[i];
        m1 = fmaxf(m1, v * as);
        m2 = fmaxf(m2, v * ad);
    }
    #pragma unroll
    for (int off = 32; off > 0; off >>= 1) {
        m1 = fmaxf(m1, __shfl_xor(m1, off));
        m2 = fmaxf(m2, __shfl_xor(m2, off));
    }
    __shared__ float bm[2][16];
    int wv = threadIdx.x >> 6;
    if ((threadIdx.x & 63) == 0) { bm[0][wv] = m1; bm[1][wv] = m2; }
    __syncthreads();
    if (threadIdx.x == 0) {
        float a = bm[0][0], bb = bm[1][0];
        for (int k = 1; k < 16; ++k) { a = fmaxf(a, bm[0][k]); bb = fmaxf(bb, bm[1][k]); }
        atomicMax(maxenc,     enc_max(a));
        atomicMax(maxenc + 1, enc_max(bb));
    }
}

// ---------- 2d) launch4: place(half2) || gather(half1 record ranges) ----------
__global__ __launch_bounds__(1024)
void place2_gather1_kernel(const int* __restrict__ src_idx, const int* __restrict__ dst_idx,
                           const float* __restrict__ h, const int* __restrict__ wbase,
                           unsigned* __restrict__ rec, int E,
                           const float* __restrict__ ad_h, const float* __restrict__ att_src,
                           const unsigned* __restrict__ maxenc,
                           const int* __restrict__ rbase,
                           unsigned long long* __restrict__ part, int SGh) {
    __shared__ int ccur[16][NBINS];
    __shared__ __align__(16) unsigned long long s_acc[BINSZ];
    int b = blockIdx.x;
    if (b < PB1024) {
        int wv = threadIdx.x >> 6;
        place_wave(src_idx, dst_idx, h, wbase, rec, E, NW / 2 + b * 16 + wv, ccur[wv]);
        return;
    }
    int gb    = b - PB1024;
    int bin   = gb / SGh;
    int slice = gb - bin * SGh;
    long long lo  = rbase[bin];
    long long mid = wbase[bin * NW + NW / 2];    // end of half-1 records for this bin
    long long cnt = mid - lo;
    long long g0 = lo + cnt * slice / SGh;
    long long g1 = lo + cnt * (slice + 1) / SGh;
    const float as = att_src[0];
    const float L  = lrelu(dec_max(maxenc[0]) + dec_max(maxenc[1]));
    gather_range(rec, ad_h + bin * BINSZ, as, L, g0, g1, s_acc,
                 part + (size_t)gb * BINSZ);
}

// ---------- 2e) launch5: gather(half2 record ranges) ----------
__global__ __launch_bounds__(1024)
void gather2_kernel(const unsigned* __restrict__ rec, const int* __restrict__ wbase,
                    const float* __restrict__ ad_h, const float* __restrict__ att_src,
                    const unsigned* __restrict__ maxenc,
                    const int* __restrict__ rbase, const int* __restrict__ hist,
                    unsigned long long* __restrict__ part, int SGh) {
    __shared__ __align__(16) unsigned long long s_acc[BINSZ];
    int gb    = blockIdx.x;
    int bin   = gb / SGh;
    int slice = gb - bin * SGh;
    long long mid = wbase[bin * NW + NW / 2];
    long long hi  = (long long)rbase[bin] + hist[bin];
    long long cnt = hi - mid;
    long long g0 = mid + cnt * slice / SGh;
    long long g1 = mid + cnt * (slice + 1) / SGh;
    const float as = att_src[0];
    const float L  = lrelu(dec_max(maxenc[0]) + dec_max(maxenc[1]));
    gather_range(rec, ad_h + bin * BINSZ, as, L, g0, g1, s_acc,
                 part + (size_t)(NBINS * SGh + gb) * BINSZ);
}

// ---------- 3) reduce copies (both halves) + self-loop + divide ----------
__global__ void reduce_final(const unsigned long long* __restrict__ part,
                             const float* __restrict__ h,
                             const float* __restrict__ att_src, const float* __restrict__ att_dst,
                             const float* __restrict__ bias, const unsigned* __restrict__ maxenc,
                             float* __restrict__ out, int n, int SGh) {
    int i = blockIdx.x * blockDim.x + threadIdx.x;
    if (i >= n) return;
    int bin = i / BINSZ;
    int off = i - bin * BINSZ;
    float num = 0.f, den = 0.f;
    const unsigned long long* p1 = part + (size_t)(bin * SGh) * BINSZ;
    const unsigned long long* p2 = part + (size_t)(NBINS * SGh + bin * SGh) * BINSZ;
    for (int s = 0; s < SGh; ++s) {
        unsigned long long v1 = __builtin_nontemporal_load(p1 + off);
        unsigned long long v2 = __builtin_nontemporal_load(p2 + off);
        num += (float)(int)(v1 >> 32) + (float)(int)(v2 >> 32);
        den += (float)(unsigned)(v1 & 0xffffffffULL) + (float)(unsigned)(v2 & 0xffffffffULL);
        p1 += BINSZ; p2 += BINSZ;
    }
    num *= INV_F_NUM;
    den *= INV_F_DEN;
    const float L = lrelu(dec_max(maxenc[0]) + dec_max(maxenc[1]));
    float hv = h[i];
    float e  = __expf(lrelu(hv * (att_src[0] + att_dst[0])) - L);
    out[i] = (num + e * hv) / (den + e + 1e-30f) + bias[0];
}

// ---------- fallback: round-3 binned multipass ----------
__global__ __launch_bounds__(1024)
void binpass_kernel(const int* __restrict__ src_idx, const int* __restrict__ dst_idx,
                    const float* __restrict__ h,
                    const float* __restrict__ att_src, const float* __restrict__ att_dst,
                    float* __restrict__ part, int E, int n, int BPB) {
    __shared__ float s_num[BINSZ];
    __shared__ float s_den[BINSZ];

    int bin   = blockIdx.x / BPB;
    int slice = blockIdx.x - bin * BPB;
    int base  = bin * BINSZ;
    int blen  = min(BINSZ, n - base);

    for (int k = threadIdx.x; k < BINSZ; k += 1024) { s_num[k] = 0.f; s_den[k] = 0.f; }
    __syncthreads();

    const float as = att_src[0];
    const float ad = att_dst[0];

    long long e0 = (long long)E * slice / BPB;
    long long e1 = (long long)E * (slice + 1) / BPB;
    for (long long i = e0 + threadIdx.x; i < e1; i += 1024) {
        int d = dst_idx[i];
        unsigned r = (unsigned)(d - base);
        if (r < (unsigned)blen) {
            int s = src_idx[i];
            float hs = h[s];
            float v  = fmaf(hs, as, h[d] * ad);
            float e  = __expf(lrelu(v));
            atomicAdd(&s_num[r], e * hs);
            atomicAdd(&s_den[r], e);
        }
    }
    __syncthreads();

    float* outp = part + (size_t)blockIdx.x * (2 * BINSZ);
    for (int k = threadIdx.x; k < BINSZ; k += 1024) {
        outp[k]         = s_num[k];
        outp[BINSZ + k] = s_den[k];
    }
}

__global__ void fb_reduce_final(const float* __restrict__ part, const float* __restrict__ h,
                                const float* __restrict__ att_src, const float* __restrict__ att_dst,
                                const float* __restrict__ bias, float* __restrict__ out,
                                int n, int BPB) {
    int i = blockIdx.x * blockDim.x + threadIdx.x;
    if (i >= n) return;
    int bin = i / BINSZ;
    int off = i - bin * BINSZ;
    float num = 0.f, den = 0.f;
    const float* p = part + (size_t)(bin * BPB) * (2 * BINSZ);
    for (int s = 0; s < BPB; ++s) {
        num += p[off];
        den += p[BINSZ + off];
        p += 2 * BINSZ;
    }
    float hv = h[i];
    float e  = __expf(lrelu(hv * (att_src[0] + att_dst[0])));
    out[i] = (num + e * hv) / (den + e + 1e-16f) + bias[0];
}

__global__ void edge_kernel(const int* __restrict__ src_idx, const int* __restrict__ dst_idx,
                            const float* __restrict__ h,
                            const float* __restrict__ att_src, const float* __restrict__ att_dst,
                            float* __restrict__ nd, int E) {
    const float as = att_src[0];
    const float ad = att_dst[0];
    int i      = blockIdx.x * blockDim.x + threadIdx.x;
    int stride = gridDim.x * blockDim.x;
    for (; i < E; i += stride) {
        int s = src_idx[i];
        int d = dst_idx[i];
        float hs = h[s];
        float e  = __expf(lrelu(fmaf(hs, as, h[d] * ad)));
        unsafeAtomicAdd(&nd[2 * d],     e * hs);
        unsafeAtomicAdd(&nd[2 * d + 1], e);
    }
}

__global__ void final_kernel(const float* __restrict__ h, const float* __restrict__ nd,
                             const float* __restrict__ att_src, const float* __restrict__ att_dst,
                             const float* __restrict__ bias, float* __restrict__ out, int n) {
    int i = blockIdx.x * blockDim.x + threadIdx.x;
    if (i >= n) return;
    float hv = h[i];
    float e  = __expf(lrelu(hv * (att_src[0] + att_dst[0])));
    out[i] = (nd[2 * i] + e * hv) / (nd[2 * i + 1] + e + 1e-16f) + bias[0];
}

extern "C" void kernel_launch(void* const* d_in, const int* in_sizes, int n_in,
                              void* d_out, int out_size, void* d_ws, size_t ws_size,
                              hipStream_t stream) {
    const float* x       = (const float*)d_in[0];
    const int*   ei      = (const int*)d_in[1];   // int64 in reference -> int32 here
    const float* W       = (const float*)d_in[2];
    const float* att_src = (const float*)d_in[3];
    const float* att_dst = (const float*)d_in[4];
    const float* bias    = (const float*)d_in[5];
    float*       out     = (float*)d_out;

    const int n = out_size;           // 100000
    const int E = in_sizes[1] / 2;    // 6400000

    const int NELEM  = NBINS * NW;    // 106496
    const int NCHUNK = NELEM / 1024;  // 104

    // ---- workspace layout ----
    size_t off = 0;
    auto alloc = [&](size_t bytes) { size_t p = off; off = (off + bytes + 255) & ~(size_t)255; return p; };
    size_t o_h    = alloc((size_t)n * sizeof(float));
    size_t o_adh  = alloc((size_t)n * sizeof(float));
    size_t o_wc   = alloc((size_t)NELEM * sizeof(int));
    size_t o_wb   = alloc((size_t)NELEM * sizeof(int));
    size_t o_bs   = alloc((size_t)NCHUNK * sizeof(int));
    size_t o_bb   = alloc((size_t)NCHUNK * sizeof(int));
    size_t o_meta = alloc(64 * sizeof(int));      // rbase[16] | hist[16] | maxenc[2]
    size_t o_rec  = alloc((size_t)E * sizeof(unsigned));
    size_t fixed  = off;

    float*    h      = (float*)((char*)d_ws + o_h);
    float*    ad_h   = (float*)((char*)d_ws + o_adh);
    int*      rbase  = (int*)((char*)d_ws + o_meta);
    int*      hist   = rbase + 16;
    unsigned* maxenc = (unsigned*)(rbase + 32);
    const size_t per = (size_t)BINSZ * sizeof(unsigned long long);   // 64000 B per partial copy

    int SGh = 0;
    if (ws_size > fixed) SGh = (int)((ws_size - fixed) / ((size_t)2 * NBINS * per));
    if (SGh > MAX_SGH) SGh = MAX_SGH;

    bool ok_shape = (n <= NBINS * BINSZ) && ((E & 3) == 0) && (E >= 4 * NW) && ((n & 1) == 0);

    if (SGh >= 4 && ok_shape) {
        // ---- primary: counting sort + fused count||proj + split-half place/gather pipeline ----
        int*                wc   = (int*)((char*)d_ws + o_wc);
        int*                wb   = (int*)((char*)d_ws + o_wb);
        int*                bsum = (int*)((char*)d_ws + o_bs);
        int*                bbase= (int*)((char*)d_ws + o_bb);
        unsigned*           rec  = (unsigned*)((char*)d_ws + o_rec);
        unsigned long long* part = (unsigned long long*)((char*)d_ws + fixed);

        count_proj_kernel<<<3072, 256, 0, stream>>>(ei + E, wc, E,
                                                    x, W, att_dst, h, ad_h, n);
        scanA_kernel<<<NCHUNK, 256, 0, stream>>>(wc, bsum);
        scanB_kernel<<<1, 128, 0, stream>>>(bsum, bbase, rbase, hist, maxenc, NCHUNK);
        scanC_kernel<<<NCHUNK, 256, 0, stream>>>(wc, bbase, wb);
        place1_hmax_kernel<<<PB1024 + HMAXB, 1024, 0, stream>>>(
            ei, ei + E, h, wb, rec, E, att_src, att_dst, maxenc, n);
        place2_gather1_kernel<<<PB1024 + NBINS * SGh, 1024, 0, stream>>>(
            ei, ei + E, h, wb, rec, E, ad_h, att_src, maxenc, rbase, part, SGh);
        gather2_kernel<<<NBINS * SGh, 1024, 0, stream>>>(
            rec, wb, ad_h, att_src, maxenc, rbase, hist, part, SGh);
        reduce_final<<<(n + 255) / 256, 256, 0, stream>>>(part, h, att_src, att_dst,
                                                          bias, maxenc, out, n, SGh);
    } else {
        // ---- fallback: round-3 multipass (f32, no normalization needed) ----
        proj_kernel<<<1024, 256, 0, stream>>>(x, W, att_dst, h, ad_h, n);
        size_t hb = (((size_t)n * 2 * sizeof(float)) + 255) & ~(size_t)255;
        int BPB = 0;
        if (ws_size > hb) BPB = (int)((ws_size - hb) / ((size_t)NBINS * per));
        if (BPB > MAX_BPB) BPB = MAX_BPB;

        if (BPB >= 6 && n <= NBINS * BINSZ) {
            float* part = (float*)((char*)d_ws + hb);
            binpass_kernel<<<NBINS * BPB, 1024, 0, stream>>>(
                ei, ei + E, h, att_src, att_dst, part, E, n, BPB);
            fb_reduce_final<<<(n + 255) / 256, 256, 0, stream>>>(
                part, h, att_src, att_dst, bias, out, n, BPB);
        } else {
            float* nd = (float*)((char*)d_ws + hb);
            hipMemsetAsync(nd, 0, (size_t)n * 2 * sizeof(float), stream);
            edge_kernel<<<2048, 256, 0, stream>>>(ei, ei + E, h, att_src, att_dst, nd, E);
            final_kernel<<<(n + 255) / 256, 256, 0, stream>>>(h, nd, att_src, att_dst,
                                                              bias, out, n);
        }
    }
}

// Round 20
// 116.100 us; speedup vs baseline: 1.0771x; 1.0771x over previous
//
#include <hip/hip_runtime.h>

#define IN_CH 128
#define NEG_SLOPE 0.2f
#define BINSZ 8000          // nodes per bin; LDS = 8000*8 = 64000 B
#define NBINS 13
#define NW 8192             // global wave count for count/place (must match grids)
#define MAX_SG 39           // 13*39 = 507 blocks ~= 2 per CU
#define MAX_BPB 40
#define PLACE_BLOCKS (NW / 4)
#define HMAX_BLOCKS 120
#define F_NUM 2097152.0f    // 2^21 fixed-point scale for num = e*hs  (|num| < 1024)
#define F_DEN 16777216.0f   // 2^24 fixed-point scale for den = e     (den < 256)
#define INV_F_NUM 4.76837158203125e-7f
#define INV_F_DEN 5.9604644775390625e-8f

typedef int   vi4 __attribute__((ext_vector_type(4)));
typedef float vf4 __attribute__((ext_vector_type(4)));

__device__ __forceinline__ float lrelu(float v) { return v > 0.f ? v : NEG_SLOPE * v; }
__device__ __forceinline__ unsigned enc_max(float f) {
    unsigned u = __float_as_uint(f);
    return (u & 0x80000000u) ? ~u : (u | 0x80000000u);   // monotone float->uint
}
__device__ __forceinline__ float dec_max(unsigned e) {
    return (e & 0x80000000u) ? __uint_as_float(e ^ 0x80000000u) : __uint_as_float(~e);
}
__device__ __forceinline__ unsigned bf16_rne(float f) {   // top-16 bits, round-nearest-even
    unsigned u = __float_as_uint(f);
    return (u + 0x7FFFu + ((u >> 16) & 1u)) >> 16;
}

// ---------- proj body (device func) ----------
__device__ __forceinline__ void do_proj(const float* __restrict__ x, const float* __restrict__ W,
                                        const float* __restrict__ att_dst,
                                        float* __restrict__ h, float* __restrict__ ad_h,
                                        int n, int wid, int nwaves) {
    int lane = threadIdx.x & 63;
    int half = lane >> 5;
    int hl   = lane & 31;

    vf4 w4 = reinterpret_cast<const vf4*>(W)[hl];
    const float ad = att_dst[0];

    int npair = n >> 1;
    for (int p0 = wid * 4; p0 < npair; p0 += nwaves * 4) {
        float s[4];
        #pragma unroll
        for (int k = 0; k < 4; ++k) {
            int p = p0 + k;
            s[k] = 0.f;
            if (p < npair) {
                int row = 2 * p + half;
                vf4 v = __builtin_nontemporal_load(
                    reinterpret_cast<const vf4*>(x + (size_t)row * IN_CH) + hl);
                s[k] = v.x * w4.x + v.y * w4.y + v.z * w4.z + v.w * w4.w;
            }
        }
        #pragma unroll
        for (int k = 0; k < 4; ++k) {
            #pragma unroll
            for (int off = 16; off > 0; off >>= 1) s[k] += __shfl_xor(s[k], off);
        }
        #pragma unroll
        for (int k = 0; k < 4; ++k) {
            int p = p0 + k;
            if (p < npair && hl == 0) {
                int row = 2 * p + half;
                h[row] = s[k];
                ad_h[row] = s[k] * ad;
            }
        }
    }
    if ((n & 1) && wid == 0) {
        int row = n - 1;
        vf4 v = reinterpret_cast<const vf4*>(x + (size_t)row * IN_CH)[hl];
        float s = v.x * w4.x + v.y * w4.y + v.z * w4.z + v.w * w4.w;
        #pragma unroll
        for (int off = 16; off > 0; off >>= 1) s += __shfl_xor(s, off);
        if (lane == 0) { h[row] = s; ad_h[row] = s * ad; }
    }
}

// ---------- standalone proj (fallback path) ----------
__global__ __launch_bounds__(256)
void proj_kernel(const float* __restrict__ x, const float* __restrict__ W,
                 const float* __restrict__ att_dst,
                 float* __restrict__ h, float* __restrict__ ad_h, int n) {
    int wid    = (blockIdx.x * blockDim.x + threadIdx.x) >> 6;
    int nwaves = (gridDim.x * blockDim.x) >> 6;
    do_proj(x, W, att_dst, h, ad_h, n, wid, nwaves);
}

// ---------- 2a) FUSED count (vec4 + per-wave LDS counters) || proj ----------
__global__ __launch_bounds__(256)
void count_proj_kernel(const int* __restrict__ dst_idx, int* __restrict__ wc, int E,
                       const float* __restrict__ x, const float* __restrict__ W,
                       const float* __restrict__ att_dst,
                       float* __restrict__ h, float* __restrict__ ad_h, int n) {
    __shared__ int cnt[4][NBINS];
    int b = blockIdx.x;
    int role = b % 3;
    if (role == 2) {
        int qid = b / 3;                       // [0,1024)
        int wid = qid * 4 + (threadIdx.x >> 6);
        do_proj(x, W, att_dst, h, ad_h, n, wid, 4096);
        return;
    }
    int pid  = (b / 3) * 2 + role;             // [0,2048)
    int lane = threadIdx.x & 63, wv = threadIdx.x >> 6;
    int g = pid * 4 + wv;                      // [0, NW)
    if (lane < NBINS) cnt[wv][lane] = 0;       // wave-private counters (no barrier needed)

    long long E4 = E >> 2;
    long long e0 = 4 * (E4 * g / NW);
    long long e1 = (g == NW - 1) ? (long long)E : 4 * (E4 * (g + 1) / NW);
    for (long long i0 = e0; i0 < e1; i0 += 256) {
        long long i = i0 + 4 * lane;
        if (i < e1) {
            vi4 d4 = __builtin_nontemporal_load(reinterpret_cast<const vi4*>(dst_idx + i));
            atomicAdd(&cnt[wv][d4.x / BINSZ], 1);
            atomicAdd(&cnt[wv][d4.y / BINSZ], 1);
            atomicAdd(&cnt[wv][d4.z / BINSZ], 1);
            atomicAdd(&cnt[wv][d4.w / BINSZ], 1);
        }
    }
    if (lane < NBINS) wc[lane * NW + g] = cnt[wv][lane];
}

// ---------- 2b) scan pipeline ----------
__global__ __launch_bounds__(256)
void scanA_kernel(const int* __restrict__ wc, int* __restrict__ bsum) {
    __shared__ int wt[4];
    int t = threadIdx.x, lane = t & 63, wv = t >> 6;
    vi4 c = *reinterpret_cast<const vi4*>(wc + blockIdx.x * 1024 + 4 * t);
    int s = c.x + c.y + c.z + c.w;
    #pragma unroll
    for (int off = 32; off > 0; off >>= 1) s += __shfl_xor(s, off);
    if (lane == 0) wt[wv] = s;
    __syncthreads();
    if (t == 0) bsum[blockIdx.x] = wt[0] + wt[1] + wt[2] + wt[3];
}

__global__ __launch_bounds__(128)
void scanB_kernel(const int* __restrict__ bsum, int* __restrict__ bbase,
                  int* __restrict__ rbase, int* __restrict__ hist,
                  unsigned* __restrict__ maxenc, int nchunk) {
    __shared__ int sb[129];
    __shared__ int wt[2];
    int t = threadIdx.x, lane = t & 63, wv = t >> 6;
    if (t < 2) maxenc[t] = 0u;                  // zero for later atomicMax (runs before hmax)
    int v = (t < nchunk) ? bsum[t] : 0;
    int inc = v;
    #pragma unroll
    for (int d2 = 1; d2 < 64; d2 <<= 1) { int u = __shfl_up(inc, d2); if (lane >= d2) inc += u; }
    if (lane == 63) wt[wv] = inc;
    __syncthreads();
    int excl = ((wv == 1) ? wt[0] : 0) + inc - v;
    sb[t] = excl;
    if (t == 127) sb[128] = excl + v;   // grand total
    __syncthreads();
    if (t < nchunk) bbase[t] = sb[t];
    if (t < NBINS) {
        int rb = sb[t * (NW / 1024)];
        rbase[t] = rb;
        int nb = (t == NBINS - 1) ? sb[128] : sb[(t + 1) * (NW / 1024)];
        hist[t] = nb - rb;
    }
}

__global__ __launch_bounds__(256)
void scanC_kernel(const int* __restrict__ wc, const int* __restrict__ bbase,
                  int* __restrict__ wbase) {
    __shared__ int wt[4];
    int t = threadIdx.x, lane = t & 63, wv = t >> 6;
    int base = blockIdx.x * 1024 + 4 * t;
    vi4 c = *reinterpret_cast<const vi4*>(wc + base);
    int s0 = c.x, s1 = s0 + c.y, s2 = s1 + c.z, s3 = s2 + c.w;
    int tot = s3;
    int inc = tot;
    #pragma unroll
    for (int d2 = 1; d2 < 64; d2 <<= 1) { int u = __shfl_up(inc, d2); if (lane >= d2) inc += u; }
    if (lane == 63) wt[wv] = inc;
    __syncthreads();
    int wb = 0;
    for (int k = 0; k < wv; ++k) wb += wt[k];
    int excl = bbase[blockIdx.x] + wb + inc - tot;
    vi4 o; o.x = excl; o.y = excl + s0; o.z = excl + s1; o.w = excl + s2;
    *reinterpret_cast<vi4*>(wbase + base) = o;
}

// ---------- 2c) FUSED place (4 edges/lane, 1-deep idx prefetch, bf16 records) || hmax ----------
__global__ __launch_bounds__(256)
void place_hmax_kernel(const int* __restrict__ src_idx, const int* __restrict__ dst_idx,
                       const float* __restrict__ h, const int* __restrict__ wbase,
                       unsigned* __restrict__ rec, int E,
                       const float* __restrict__ att_src, const float* __restrict__ att_dst,
                       unsigned* __restrict__ maxenc, int n) {
    int b = blockIdx.x;
    if (b >= PLACE_BLOCKS) {
        // ---- hmax role: global max of h*att_src and h*att_dst ----
        int bid = b - PLACE_BLOCKS;             // [0, HMAX_BLOCKS)
        const float as = att_src[0];
        const float ad = att_dst[0];
        float m1 = -1e30f, m2 = -1e30f;
        for (int i = bid * 256 + threadIdx.x; i < n; i += HMAX_BLOCKS * 256) {
            float v = h[i];
            m1 = fmaxf(m1, v * as);
            m2 = fmaxf(m2, v * ad);
        }
        #pragma unroll
        for (int off = 32; off > 0; off >>= 1) {
            m1 = fmaxf(m1, __shfl_xor(m1, off));
            m2 = fmaxf(m2, __shfl_xor(m2, off));
        }
        __shared__ float bm[2][4];
        int wv = threadIdx.x >> 6;
        if ((threadIdx.x & 63) == 0) { bm[0][wv] = m1; bm[1][wv] = m2; }
        __syncthreads();
        if (threadIdx.x == 0) {
            float a = fmaxf(fmaxf(bm[0][0], bm[0][1]), fmaxf(bm[0][2], bm[0][3]));
            float bmax = fmaxf(fmaxf(bm[1][0], bm[1][1]), fmaxf(bm[1][2], bm[1][3]));
            atomicMax(maxenc,     enc_max(a));
            atomicMax(maxenc + 1, enc_max(bmax));
        }
        return;
    }

    // ---- place role: 4 edges/lane/iter, next-iter idx prefetched ----
    __shared__ int ccur[4][NBINS];
    int lane = threadIdx.x & 63, wv = threadIdx.x >> 6;
    int g = b * 4 + wv;
    if (lane < NBINS) ccur[wv][lane] = wbase[lane * NW + g];
    __syncthreads();

    long long E4 = E >> 2;
    long long e0 = 4 * (E4 * g / NW);
    long long e1 = (g == NW - 1) ? (long long)E : 4 * (E4 * (g + 1) / NW);

    long long i = e0 + 4 * (long long)lane;
    bool have = (i < e1);
    vi4 d4 = {0,0,0,0}, s4 = {0,0,0,0};
    if (have) {
        d4 = __builtin_nontemporal_load(reinterpret_cast<const vi4*>(dst_idx + i));
        s4 = __builtin_nontemporal_load(reinterpret_cast<const vi4*>(src_idx + i));
    }
    while (have) {
        long long nx = i + 256;
        bool nhave = (nx < e1);
        vi4 d4n = {0,0,0,0}, s4n = {0,0,0,0};
        if (nhave) {                            // prefetch next iteration's indices
            d4n = __builtin_nontemporal_load(reinterpret_cast<const vi4*>(dst_idx + nx));
            s4n = __builtin_nontemporal_load(reinterpret_cast<const vi4*>(src_idx + nx));
        }
        float h0 = h[s4.x], h1 = h[s4.y], h2 = h[s4.z], h3 = h[s4.w];
        int b0 = d4.x / BINSZ, b1 = d4.y / BINSZ, b2 = d4.z / BINSZ, b3 = d4.w / BINSZ;
        int p0 = atomicAdd(&ccur[wv][b0], 1);
        int p1 = atomicAdd(&ccur[wv][b1], 1);
        int p2 = atomicAdd(&ccur[wv][b2], 1);
        int p3 = atomicAdd(&ccur[wv][b3], 1);
        rec[p0] = ((unsigned)(d4.x - b0 * BINSZ) << 16) | bf16_rne(h0);  // normal stores:
        rec[p1] = ((unsigned)(d4.y - b1 * BINSZ) << 16) | bf16_rne(h1);  // L2 write-combines
        rec[p2] = ((unsigned)(d4.z - b2 * BINSZ) << 16) | bf16_rne(h2);
        rec[p3] = ((unsigned)(d4.w - b3 * BINSZ) << 16) | bf16_rne(h3);
        i = nx; d4 = d4n; s4 = s4n; have = nhave;
    }
}

// ---------- 2d) gather: PURE streaming (hs in record), ONE u64 LDS atomic/record ----------
__global__ __launch_bounds__(1024)
void gather_kernel(const unsigned* __restrict__ rec,
                   const float* __restrict__ ad_h,
                   const float* __restrict__ att_src, const unsigned* __restrict__ maxenc,
                   const int* __restrict__ rbase, const int* __restrict__ hist,
                   unsigned long long* __restrict__ part, int SG) {
    __shared__ __align__(16) unsigned long long s_acc[BINSZ];  // packed {num:i32.21 | den:u32.24}

    int bin   = blockIdx.x / SG;
    int slice = blockIdx.x - bin * SG;
    long long r0 = rbase[bin];
    int cnt   = hist[bin];
    long long g0 = r0 + (long long)cnt * slice / SG;
    long long g1 = r0 + (long long)cnt * (slice + 1) / SG;

    {   // zero LDS with 16B stores
        vi4 z = {0, 0, 0, 0};
        for (int k = threadIdx.x; k < BINSZ / 2; k += 1024)
            *reinterpret_cast<vi4*>(&s_acc[2 * k]) = z;
    }
    __syncthreads();

    const float as = att_src[0];
    const float L  = lrelu(dec_max(maxenc[0]) + dec_max(maxenc[1]));   // logit upper bound
    const float* adw = ad_h + bin * BINSZ;   // 32 KB window

    auto process1 = [&](unsigned q) {
        int ri = q >> 16;                               // r in bits 16..28
        float h0 = __uint_as_float(q << 16);            // bf16 -> f32
        float e0 = __expf(lrelu(fmaf(h0, as, adw[ri])) - L);
        unsigned long long p0 = ((unsigned long long)(long long)__float2int_rn(e0 * h0 * F_NUM) << 32)
                              + __float2uint_rn(e0 * F_DEN);
        atomicAdd(&s_acc[ri], p0);
    };

    long long a0 = (g0 + 3) & ~3LL;     // aligned vector range [a0, a1)
    long long a1 = g1 & ~3LL;
    long long headEnd, tail0;
    if (a0 <= a1) { headEnd = a0; tail0 = a1; }
    else          { headEnd = g1; tail0 = g1; a0 = 0; a1 = 0; }

    for (long long i = g0 + threadIdx.x; i < headEnd; i += 1024) process1(rec[i]);

    // 1-deep prefetch on the rec stream (only memory access in the loop)
    long long i = a0 + 4 * (long long)threadIdx.x;
    vi4 q = {0,0,0,0};
    bool have = (i < a1);
    if (have) q = __builtin_nontemporal_load(reinterpret_cast<const vi4*>(rec + i));
    while (have) {
        long long nx = i + 4096;
        bool nhave = (nx < a1);
        vi4 nq = {0,0,0,0};
        if (nhave) nq = __builtin_nontemporal_load(reinterpret_cast<const vi4*>(rec + nx));
        unsigned u0=(unsigned)q.x, u1=(unsigned)q.y, u2=(unsigned)q.z, u3=(unsigned)q.w;
        int r0i=u0>>16, r1i=u1>>16, r2i=u2>>16, r3i=u3>>16;
        float h0=__uint_as_float(u0<<16), h1=__uint_as_float(u1<<16);
        float h2=__uint_as_float(u2<<16), h3=__uint_as_float(u3<<16);
        float e0 = __expf(lrelu(fmaf(h0, as, adw[r0i])) - L);
        float e1 = __expf(lrelu(fmaf(h1, as, adw[r1i])) - L);
        float e2 = __expf(lrelu(fmaf(h2, as, adw[r2i])) - L);
        float e3 = __expf(lrelu(fmaf(h3, as, adw[r3i])) - L);
        unsigned long long p0 = ((unsigned long long)(long long)__float2int_rn(e0 * h0 * F_NUM) << 32) + __float2uint_rn(e0 * F_DEN);
        unsigned long long p1 = ((unsigned long long)(long long)__float2int_rn(e1 * h1 * F_NUM) << 32) + __float2uint_rn(e1 * F_DEN);
        unsigned long long p2 = ((unsigned long long)(long long)__float2int_rn(e2 * h2 * F_NUM) << 32) + __float2uint_rn(e2 * F_DEN);
        unsigned long long p3 = ((unsigned long long)(long long)__float2int_rn(e3 * h3 * F_NUM) << 32) + __float2uint_rn(e3 * F_DEN);
        atomicAdd(&s_acc[r0i], p0);
        atomicAdd(&s_acc[r1i], p1);
        atomicAdd(&s_acc[r2i], p2);
        atomicAdd(&s_acc[r3i], p3);
        i = nx; q = nq; have = nhave;
    }

    for (long long i2 = tail0 + threadIdx.x; i2 < g1; i2 += 1024) process1(rec[i2]);
    __syncthreads();

    unsigned long long* outp = part + (size_t)blockIdx.x * BINSZ;
    for (int k = threadIdx.x; k < BINSZ / 2; k += 1024) {
        vi4 v = *reinterpret_cast<const vi4*>(&s_acc[2 * k]);
        __builtin_nontemporal_store(v, reinterpret_cast<vi4*>(outp + 2 * k));
    }
}

// ---------- 3) reduce copies (unpack fixed point) + self-loop + divide ----------
__global__ void reduce_final(const unsigned long long* __restrict__ part,
                             const float* __restrict__ h,
                             const float* __restrict__ att_src, const float* __restrict__ att_dst,
                             const float* __restrict__ bias, const unsigned* __restrict__ maxenc,
                             float* __restrict__ out, int n, int SG) {
    int i = blockIdx.x * blockDim.x + threadIdx.x;
    if (i >= n) return;
    int bin = i / BINSZ;
    int off = i - bin * BINSZ;
    float num = 0.f, den = 0.f;
    const unsigned long long* p = part + (size_t)(bin * SG) * BINSZ;
    for (int s = 0; s < SG; ++s) {
        unsigned long long v = __builtin_nontemporal_load(p + off);
        num += (float)(int)(v >> 32);
        den += (float)(unsigned)(v & 0xffffffffULL);
        p += BINSZ;
    }
    num *= INV_F_NUM;
    den *= INV_F_DEN;
    const float L = lrelu(dec_max(maxenc[0]) + dec_max(maxenc[1]));
    float hv = h[i];
    float e  = __expf(lrelu(hv * (att_src[0] + att_dst[0])) - L);
    out[i] = (num + e * hv) / (den + e + 1e-30f) + bias[0];
}

// ---------- fallback: round-3 binned multipass ----------
__global__ __launch_bounds__(1024)
void binpass_kernel(const int* __restrict__ src_idx, const int* __restrict__ dst_idx,
                    const float* __restrict__ h,
                    const float* __restrict__ att_src, const float* __restrict__ att_dst,
                    float* __restrict__ part, int E, int n, int BPB) {
    __shared__ float s_num[BINSZ];
    __shared__ float s_den[BINSZ];

    int bin   = blockIdx.x / BPB;
    int slice = blockIdx.x - bin * BPB;
    int base  = bin * BINSZ;
    int blen  = min(BINSZ, n - base);

    for (int k = threadIdx.x; k < BINSZ; k += 1024) { s_num[k] = 0.f; s_den[k] = 0.f; }
    __syncthreads();

    const float as = att_src[0];
    const float ad = att_dst[0];

    long long e0 = (long long)E * slice / BPB;
    long long e1 = (long long)E * (slice + 1) / BPB;
    for (long long i = e0 + threadIdx.x; i < e1; i += 1024) {
        int d = dst_idx[i];
        unsigned r = (unsigned)(d - base);
        if (r < (unsigned)blen) {
            int s = src_idx[i];
            float hs = h[s];
            float v  = fmaf(hs, as, h[d] * ad);
            float e  = __expf(lrelu(v));
            atomicAdd(&s_num[r], e * hs);
            atomicAdd(&s_den[r], e);
        }
    }
    __syncthreads();

    float* outp = part + (size_t)blockIdx.x * (2 * BINSZ);
    for (int k = threadIdx.x; k < BINSZ; k += 1024) {
        outp[k]         = s_num[k];
        outp[BINSZ + k] = s_den[k];
    }
}

__global__ void fb_reduce_final(const float* __restrict__ part, const float* __restrict__ h,
                                const float* __restrict__ att_src, const float* __restrict__ att_dst,
                                const float* __restrict__ bias, float* __restrict__ out,
                                int n, int BPB) {
    int i = blockIdx.x * blockDim.x + threadIdx.x;
    if (i >= n) return;
    int bin = i / BINSZ;
    int off = i - bin * BINSZ;
    float num = 0.f, den = 0.f;
    const float* p = part + (size_t)(bin * BPB) * (2 * BINSZ);
    for (int s = 0; s < BPB; ++s) {
        num += p[off];
        den += p[BINSZ + off];
        p += 2 * BINSZ;
    }
    float hv = h[i];
    float e  = __expf(lrelu(hv * (att_src[0] + att_dst[0])));
    out[i] = (num + e * hv) / (den + e + 1e-16f) + bias[0];
}

__global__ void edge_kernel(const int* __restrict__ src_idx, const int* __restrict__ dst_idx,
                            const float* __restrict__ h,
                            const float* __restrict__ att_src, const float* __restrict__ att_dst,
                            float* __restrict__ nd, int E) {
    const float as = att_src[0];
    const float ad = att_dst[0];
    int i      = blockIdx.x * blockDim.x + threadIdx.x;
    int stride = gridDim.x * blockDim.x;
    for (; i < E; i += stride) {
        int s = src_idx[i];
        int d = dst_idx[i];
        float hs = h[s];
        float e  = __expf(lrelu(fmaf(hs, as, h[d] * ad)));
        unsafeAtomicAdd(&nd[2 * d],     e * hs);
        unsafeAtomicAdd(&nd[2 * d + 1], e);
    }
}

__global__ void final_kernel(const float* __restrict__ h, const float* __restrict__ nd,
                             const float* __restrict__ att_src, const float* __restrict__ att_dst,
                             const float* __restrict__ bias, float* __restrict__ out, int n) {
    int i = blockIdx.x * blockDim.x + threadIdx.x;
    if (i >= n) return;
    float hv = h[i];
    float e  = __expf(lrelu(hv * (att_src[0] + att_dst[0])));
    out[i] = (nd[2 * i] + e * hv) / (nd[2 * i + 1] + e + 1e-16f) + bias[0];
}

extern "C" void kernel_launch(void* const* d_in, const int* in_sizes, int n_in,
                              void* d_out, int out_size, void* d_ws, size_t ws_size,
                              hipStream_t stream) {
    const float* x       = (const float*)d_in[0];
    const int*   ei      = (const int*)d_in[1];   // int64 in reference -> int32 here
    const float* W       = (const float*)d_in[2];
    const float* att_src = (const float*)d_in[3];
    const float* att_dst = (const float*)d_in[4];
    const float* bias    = (const float*)d_in[5];
    float*       out     = (float*)d_out;

    const int n = out_size;           // 100000
    const int E = in_sizes[1] / 2;    // 6400000

    const int NELEM  = NBINS * NW;    // 106496
    const int NCHUNK = NELEM / 1024;  // 104

    // ---- workspace layout ----
    size_t off = 0;
    auto alloc = [&](size_t bytes) { size_t p = off; off = (off + bytes + 255) & ~(size_t)255; return p; };
    size_t o_h    = alloc((size_t)n * sizeof(float));
    size_t o_adh  = alloc((size_t)n * sizeof(float));
    size_t o_wc   = alloc((size_t)NELEM * sizeof(int));
    size_t o_wb   = alloc((size_t)NELEM * sizeof(int));
    size_t o_bs   = alloc((size_t)NCHUNK * sizeof(int));
    size_t o_bb   = alloc((size_t)NCHUNK * sizeof(int));
    size_t o_meta = alloc(64 * sizeof(int));      // rbase[16] | hist[16] | maxenc[2]
    size_t o_rec  = alloc((size_t)E * sizeof(unsigned));
    size_t fixed  = off;

    float*    h      = (float*)((char*)d_ws + o_h);
    float*    ad_h   = (float*)((char*)d_ws + o_adh);
    int*      rbase  = (int*)((char*)d_ws + o_meta);
    int*      hist   = rbase + 16;
    unsigned* maxenc = (unsigned*)(rbase + 32);
    const size_t per = (size_t)BINSZ * sizeof(unsigned long long);   // 64000 B per partial copy

    int SG = 0;
    if (ws_size > fixed) SG = (int)((ws_size - fixed) / ((size_t)NBINS * per));
    if (SG > MAX_SG) SG = MAX_SG;

    bool ok_shape = (n <= NBINS * BINSZ) && ((E & 3) == 0) && (E >= 4 * NW) && ((n & 1) == 0);

    if (SG >= 8 && ok_shape) {
        // ---- primary: counting sort + fused count||proj + fused place||hmax + streaming gather ----
        int*                wc   = (int*)((char*)d_ws + o_wc);
        int*                wb   = (int*)((char*)d_ws + o_wb);
        int*                bsum = (int*)((char*)d_ws + o_bs);
        int*                bbase= (int*)((char*)d_ws + o_bb);
        unsigned*           rec  = (unsigned*)((char*)d_ws + o_rec);
        unsigned long long* part = (unsigned long long*)((char*)d_ws + fixed);

        count_proj_kernel<<<3072, 256, 0, stream>>>(ei + E, wc, E,
                                                    x, W, att_dst, h, ad_h, n);
        scanA_kernel<<<NCHUNK, 256, 0, stream>>>(wc, bsum);
        scanB_kernel<<<1, 128, 0, stream>>>(bsum, bbase, rbase, hist, maxenc, NCHUNK);
        scanC_kernel<<<NCHUNK, 256, 0, stream>>>(wc, bbase, wb);
        place_hmax_kernel<<<PLACE_BLOCKS + HMAX_BLOCKS, 256, 0, stream>>>(
            ei, ei + E, h, wb, rec, E, att_src, att_dst, maxenc, n);
        gather_kernel<<<NBINS * MAX_SG > NBINS * SG ? NBINS * SG : NBINS * SG, 1024, 0, stream>>>(
            rec, ad_h, att_src, maxenc, rbase, hist, part, SG);
        reduce_final<<<(n + 255) / 256, 256, 0, stream>>>(part, h, att_src, att_dst,
                                                          bias, maxenc, out, n, SG);
    } else {
        // ---- fallback: round-3 multipass (f32, no normalization needed) ----
        proj_kernel<<<1024, 256, 0, stream>>>(x, W, att_dst, h, ad_h, n);
        size_t hb = (((size_t)n * 2 * sizeof(float)) + 255) & ~(size_t)255;
        int BPB = 0;
        if (ws_size > hb) BPB = (int)((ws_size - hb) / ((size_t)NBINS * per));
        if (BPB > MAX_BPB) BPB = MAX_BPB;

        if (BPB >= 6 && n <= NBINS * BINSZ) {
            float* part = (float*)((char*)d_ws + hb);
            binpass_kernel<<<NBINS * BPB, 1024, 0, stream>>>(
                ei, ei + E, h, att_src, att_dst, part, E, n, BPB);
            fb_reduce_final<<<(n + 255) / 256, 256, 0, stream>>>(
                part, h, att_src, att_dst, bias, out, n, BPB);
        } else {
            float* nd = (float*)((char*)d_ws + hb);
            hipMemsetAsync(nd, 0, (size_t)n * 2 * sizeof(float), stream);
            edge_kernel<<<2048, 256, 0, stream>>>(ei, ei + E, h, att_src, att_dst, nd, E);
            final_kernel<<<(n + 255) / 256, 256, 0, stream>>>(h, nd, att_src, att_dst,
                                                              bias, out, n);
        }
    }
}